// Round 3
// baseline (624.674 us; speedup 1.0000x reference)
//
#include <hip/hip_runtime.h>

// CTC batch cost, linear domain, TWO WAVES per batch element (state split).
// r0-r2 post-mortems: single wave pinned at ~286cy/step (issue ~155cy +
// ~130cy un-hidden latency), Occupancy 2.8% = 1 wave/CU. B=256 on 256 CUs
// caps TLP at 1 wave/CU unless we parallelize within the element. CTC's DP
// is serial in t but the 201 states split cleanly: flow is strictly left->
// right, so a trailing wave needs only the leader's boundary state, with
// arbitrary slack.
//
//   wave0 "leader": states 0..73 (lanes 0..36, 2 states/lane: blank 2k,
//     label 2k+1), plus ALL global->LDS row staging (it runs ahead).
//     Publishes (a1_state73, e) per step to an LDS ring slot (n & 127).
//   wave1 "trailer": states 74..200 (64 lanes, 2 states/lane), runs LAG=64
//     wall-steps behind; lane0's left halo comes from the ring (read with
//     2-step slack, written >=27 steps + >=1 barrier earlier), other lanes
//     via __shfl_up exactly as before (G=1 skew, 2-step slack, r0-proven).
//
// Sync: __syncthreads() every 16 steps (72 chunks of 16). Margins (verified
// in-chunk, drift <=16+16): prob-ring write row n+15 vs trailer oldest read
// row w-127 -> gap >=49 rows, span 165 < NSLOT=192; hal ring gap >=12 of
// 128 slots. Every cross-wave read is >=1 barrier after its write (barrier
// includes the lgkm drain -> release/acquire).
//
// Exactness: same DP ops on pow2-scaled mantissas; renorm over 2 states
// (not 4) changes only exact pow2 exponents, never rounding -> bit-identical
// to the absmax-0.0 lineage. rowbuf+hal pre-zeroed: early wrapped-slot reads
// return 0.0 (not garbage/NaN) so no index clamping is needed; all zero
// slots are overwritten only long after their last wrapped read (slot>=130
// first overwritten at wall 115; wrapped reads of it end by wall 65).
//
// Per-lane recurrence (2 states): n0 = (a0 + h)*pb; n1 = (a1 + a0 + ms*h)*p0
// with per-lane exponent e (alpha = a*2^e), renorm every 4 steps.

#define Bc 256
#define Tc 1024
#define Cc 128
#define Uc 100
#define BLANKc 127
#define EPSc 1e-7f
#define LN2f 0.69314718055994530942f
#define RSTRIDE 130            // floats per row slot
#define NSLOT 192              // ring depth (span needed: 165)
#define SLOTW (NSLOT*RSTRIDE)  // 24960 words = 99840 B
#define QD 8                   // global->LDS staging queue depth
#define HRING 128              // boundary (a1,e) ring slots
#define NCHUNK 72              // 72*16 = 1152 wall steps

__global__ __launch_bounds__(128) void ctc_dual_kernel(
    const float* __restrict__ y_pred,     // [B,T,C] post-softmax probs
    const int*   __restrict__ y_true,     // [B,U]
    const int*   __restrict__ label_len,  // [B]
    float*       __restrict__ out)        // [B,1]
{
    __shared__ float  rowbuf[SLOTW];      // 99840 B circular row cache
    __shared__ float2 hal[HRING];         // (a1, bitcast e) boundary ring
    __shared__ float  shA[204];
    __shared__ int    shE[128];

    const int tid  = threadIdx.x;
    const int wid  = tid >> 6;
    const int lane = tid & 63;
    const int b    = blockIdx.x;
    const float* gp = y_pred + (size_t)b * (Tc * Cc);

    // ---- pre-zero ring + hal (makes early wrapped reads exact zeros) ----
    for (int i = 0; i < SLOTW/128; ++i) rowbuf[i*128 + tid] = 0.f;  // 195*128
    if (tid < HRING) hal[tid] = make_float2(0.f, __int_as_float(0));

    // ---- pre-stage rows 0..15 (both waves, coalesced float4) ----
#pragma unroll
    for (int i = 0; i < 4; ++i) {
        const int f4  = i*128 + tid;       // 512 float4 across 16 rows
        const int row = f4 >> 5;
        const int c4  = (f4 & 31) * 4;
        const float4 v = *(const float4*)(gp + row*Cc + c4);
        float* dst = &rowbuf[row*RSTRIDE + c4];
        dst[0]=v.x; dst[1]=v.y; dst[2]=v.z; dst[3]=v.w;
    }

    // ---- per-lane labels & masks ----
    int yme; float ms, mh;
    if (wid == 0) {                        // states 2*lane, 2*lane+1
        yme = y_true[b*Uc + lane];         // label index = lane (<=63<U)
        const int yl = (lane > 0) ? y_true[b*Uc + lane - 1] : yme;
        ms = (lane > 0 && yme != yl) ? 1.0f : 0.0f;
        mh = (lane > 0) ? 1.0f : 0.0f;
    } else {                               // states 74+2*lane, 75+2*lane
        const int li = 37 + lane;          // label index (lane63 -> ghost)
        yme = y_true[b*Uc + (li > Uc-1 ? Uc-1 : li)];
        const int yl = y_true[b*Uc + (li - 1 > Uc-1 ? Uc-1 : li - 1)];
        ms = (yme != yl) ? 1.0f : 0.0f;    // lane63 value never read
        mh = 1.0f;                         // lane0 halo comes from the ring
    }

    // ---- t=0 init: only global state 0,1 (leader lane 0) ----
    float a0 = 0.f, a1 = 0.f; int e = 0;
    if (wid == 0 && lane == 0) { a0 = gp[BLANKc]+EPSc; a1 = gp[yme]+EPSc; }

    // ---- per-lane row-slot word offset (row = step - lane, mod NSLOT) ----
    int sw = ((1 - lane + NSLOT) % NSLOT) * RSTRIDE - RSTRIDE; // pre-decrement
    if (sw < 0) sw += SLOTW;

    // ---- leader-only staging state: rows 16..23 in flight ----
    float2 Q[QD];
    int wslot = 16 * RSTRIDE;              // slot word-offset of row 16
    if (wid == 0) {
#pragma unroll
        for (int k = 0; k < QD; ++k)
            Q[k] = *(const float2*)(gp + (16+k)*Cc + lane*2);
    }
    __syncthreads();                       // staging + zeros visible to both

    // ---- halo pipes (2-step shuffle slack; ring regs for trailer lane0) ----
    float q2a = 0.f, q1a = 0.f; int q2e = 0, q1e = 0;
    float r2a = 0.f, r1a = 0.f; int r2e = 0, r1e = 0;

    // ================= leader step =================
    auto lstep = [&](int n, int j, bool fzp) {
        sw += RSTRIDE; if (sw >= SLOTW) sw -= SLOTW;       // row n - lane
        const float pbr = rowbuf[sw + BLANKc];
        const float p0r = rowbuf[sw + yme];
        // stage row n+15 (loaded 8 steps ago), reload row min(n+23,1023)
        const int qi = (n-1) & (QD-1);
        *(float2*)&rowbuf[wslot + lane*2] = Q[qi];
        wslot += RSTRIDE; if (wslot >= SLOTW) wslot -= SLOTW;
        int lr = n + 23; lr = lr > Tc-1 ? Tc-1 : lr;
        Q[qi] = *(const float2*)(gp + lr*Cc + lane*2);
        // in-wave halo from left lane's step n-2
        const float h1r = q2a; const int el = q2e;
        q2a = q1a; q2e = q1e;
        int d = el - e; d = d > 126 ? 126 : d;
        const float h1 = mh * ldexpf(h1r, d);
        const float pb = pbr + EPSc, p0 = p0r + EPSc;
        const float n0 = (a0 + h1) * pb;
        const float n1 = (a1 + a0 + ms*h1) * p0;
        const float sm = n0 + n1;
        const int   en = (sm > 0.0f) ? e : el;             // dormant: track el
        bool upd = true;
        if (fzp) upd = (lane >= n - (Tc-1));               // freeze t>1023
        if (upd) { a0 = n0; a1 = n1; e = en; }
        if ((j & 3) == 3) {                                // renorm (pow2)
            const float m = fmaxf(a0, a1);
            int ex = (int)((__float_as_uint(m) >> 23) & 0xFF) - 127;
            ex = (m > 0.0f) ? ex : 0;
            a0 = ldexpf(a0, -ex); a1 = ldexpf(a1, -ex);
            e += ex;
        }
        // publish boundary state 73 (post-renorm pair)
        if (lane == 36) hal[n & (HRING-1)] = make_float2(a1, __int_as_float(e));
        q1a = __shfl_up(a1, 1, 64);
        q1e = __shfl_up(e , 1, 64);
    };

    // ================= trailer step =================
    auto tstep = [&](int m, int j, bool fzp) {
        sw += RSTRIDE; if (sw >= SLOTW) sw -= SLOTW;       // row m - lane
        const float pbr = rowbuf[sw + BLANKc];
        const float p0r = rowbuf[sw + yme];
        // halo: lane0 from boundary ring, others from shuffle
        const float h1r = (lane == 0) ? r2a : q2a;
        const int   el  = (lane == 0) ? r2e : q2e;
        q2a = q1a; q2e = q1e;
        r2a = r1a; r2e = r1e;
        {   // issue ring read for step m+2 (slot m+37, written >=27 steps ago)
            const float2 hv = hal[(m + 37) & (HRING-1)];
            r1a = hv.x; r1e = __float_as_int(hv.y);
        }
        int d = el - e; d = d > 126 ? 126 : d;
        const float h1 = ldexpf(h1r, d);                   // mh==1 everywhere
        const float pb = pbr + EPSc, p0 = p0r + EPSc;
        const float n0 = (a0 + h1) * pb;
        const float n1 = (a1 + a0 + ms*h1) * p0;
        const float sm = n0 + n1;
        const int   en = (sm > 0.0f) ? e : el;
        bool upd = true;
        if (fzp) upd = (lane >= m - (Tc-1));
        if (upd) { a0 = n0; a1 = n1; e = en; }
        if ((j & 3) == 3) {
            const float mx = fmaxf(a0, a1);
            int ex = (int)((__float_as_uint(mx) >> 23) & 0xFF) - 127;
            ex = (mx > 0.0f) ? ex : 0;
            a0 = ldexpf(a0, -ex); a1 = ldexpf(a1, -ex);
            e += ex;
        }
        q1a = __shfl_up(a1, 1, 64);
        q1e = __shfl_up(e , 1, 64);
    };

    // ================= wall loop: 72 chunks of 16 =================
    int n = 1, m = 1;
    for (int c = 0; c < NCHUNK; ++c) {
        if (wid == 0) {
            if (c >= 63) {
#pragma unroll
                for (int j = 0; j < 16; ++j) { lstep(n, j, true);  ++n; }
            } else {
#pragma unroll
                for (int j = 0; j < 16; ++j) { lstep(n, j, false); ++n; }
            }
        } else if (c >= 4) {                               // LAG = 64
            if (c == 4) {                                  // prefill ring pipe
                float2 h2 = hal[36], h1v = hal[37];        // m=1 -> slot 36
                r2a = h2.x;  r2e = __float_as_int(h2.y);
                r1a = h1v.x; r1e = __float_as_int(h1v.y);
            }
            if (c >= 67) {
#pragma unroll
                for (int j = 0; j < 16; ++j) { tstep(m, j, true);  ++m; }
            } else {
#pragma unroll
                for (int j = 0; j < 16; ++j) { tstep(m, j, false); ++m; }
            }
        }
        __syncthreads();
    }

    // ---- epilogue: loss = -ln( A[2L-1] + A[2L] ), A = a * 2^e ----
    if (wid == 0) {
        if (lane <= 36) {
            shA[2*lane]   = a0; shA[2*lane+1] = a1;
            shE[lane]     = e;
        }
    } else {
        shA[74 + 2*lane] = a0; shA[75 + 2*lane] = a1;
        shE[64 + lane]   = e;
    }
    __syncthreads();
    if (tid == 0) {
        const int L  = label_len[b];
        const int s1 = 2*L - 1, s2 = 2*L;
        const float v1 = shA[s1], v2 = shA[s2];
        const int e1 = shE[s1 < 74 ? (s1 >> 1) : 64 + ((s1 - 74) >> 1)];
        const int e2 = shE[s2 < 74 ? (s2 >> 1) : 64 + ((s2 - 74) >> 1)];
        const int em = e1 > e2 ? e1 : e2;
        const float sum = ldexpf(v1, e1-em) + ldexpf(v2, e2-em);
        out[b] = -LN2f * (__log2f(sum) + (float)em);
    }
}

extern "C" void kernel_launch(void* const* d_in, const int* in_sizes, int n_in,
                              void* d_out, int out_size, void* d_ws, size_t ws_size,
                              hipStream_t stream) {
    const float* y_pred    = (const float*)d_in[0];
    const int*   y_true    = (const int*)d_in[1];
    const int*   label_len = (const int*)d_in[2];
    float*       out       = (float*)d_out;
    ctc_dual_kernel<<<Bc, 128, 0, stream>>>(y_pred, y_true, label_len, out);
}

// Round 4
// 251.994 us; speedup vs baseline: 2.4789x; 2.4789x over previous
//
#include <hip/hip_runtime.h>

// CTC batch cost, linear-domain, single wave per batch element, DIAGONAL SKEW.
// Lane L owns states 4L..4L+3 (S=201); at wave-step n it computes time t=n-L.
// ROUND 4: instruction-count reduction. r0-r3 established that per-step cost
// tracks the instruction count at ~4.4cy/instr (ILP~1, single wave, nothing
// hides VALU dep latency); DS-schedule changes (r1 prefetch, r2 slack) were
// neutral. So: halve the stream, keep the proven structure.
//   - e-shuffle every 4 steps (e only changes at renorms). Two EL regs rotate
//     at j in {3,7,11,15}; consumers select compile-time by j (epoch map
//     verified j=0..15: consumer at n needs producer epoch floor((n-2)/4)).
//   - dormant-lane exponent adoption folded into the renorm (ex = m>0 ? ex :
//     el-e). Dormant (a=0) decompositions may drift by pow2 vs the old
//     per-step tracking, but every renorm re-normalizes mantissa to [1,2) so
//     (a,e) re-converge bit-exactly; consumed pairs are always consistent ->
//     true alphas bit-identical (absmax 0.0 lineage preserved).
//   - incremental LDS byte offsets (one add + wrap cndmask) instead of
//     per-step recompute; negative/wrapped rows read PRE-ZEROED slots
//     (dormant lanes: 0*(junk)=0 exact, no NaN, no clamp needed).
//   - EPS pre-added at staging (all 128 classes) -> gathers return p+EPS.
//   - Q[] indexed by j&7 (compile-time), uniform write-slot/reload-row kept
//     scalar (SALU). Drain tail trimmed to n=1073 (lane 50 ends t=1023).
//
// Recurrence (unchanged):
//   n0 = (a0 + h1) * pb
//   n1 = (a1 + a0 + ms1*h1) * p_lab0
//   n2 = (a2 + a1) * pb
//   n3 = (a3 + a2 + ms3*a1) * p_lab1
// per-lane exponent e (true alpha = a*2^e), renorm every 4 steps (every-8
// rejected: probs can be ~2^-23, 8 steps could underflow 2^-126 mantissas).

#define Bc 256
#define Tc 1024
#define Cc 128
#define Uc 100
#define BLANKc 127
#define EPSc 1e-7f
#define LN2f 0.69314718055994530942f
#define RSTRIDE 130            // floats per row slot (pad: bank de-phasing)
#define NSLOT 128              // circular buffer depth (live span ~80 rows)
#define SLOTB (NSLOT*RSTRIDE*4)  // 66560 bytes
#define QD 8                   // global->LDS staging queue depth

__global__ __launch_bounds__(64) void ctc_skew_kernel(
    const float* __restrict__ y_pred,     // [B,T,C] post-softmax probs
    const int*   __restrict__ y_true,     // [B,U]
    const int*   __restrict__ label_len,  // [B]
    float*       __restrict__ out)        // [B,1]
{
    __shared__ __align__(16) float rowbuf[NSLOT * RSTRIDE];
    __shared__ float shA[204];
    __shared__ int   shE[64];

    const int b    = blockIdx.x;
    const int lane = threadIdx.x;                  // 0..63
    const float* gp = y_pred + (size_t)b * (Tc * Cc);
    char* rb = (char*)rowbuf;

    // ---- per-lane label classes & skip masks (time-invariant) ----
    const int k0  = 2*lane, k1 = 2*lane+1;
    const int k0c = k0 < Uc ? k0 : Uc-1;
    const int k1c = k1 < Uc ? k1 : Uc-1;
    const int y0  = y_true[b*Uc + k0c];            // class of state 4L+1
    const int y1  = y_true[b*Uc + k1c];            // class of state 4L+3
    int ym1 = y0;
    if (lane > 0) ym1 = y_true[b*Uc + k0 - 1];
    const float ms1 = (lane > 0 && y0 != ym1) ? 1.0f : 0.0f;
    const float ms3 = (y1 != y0) ? 1.0f : 0.0f;
    const float mh  = (lane > 0) ? 1.0f : 0.0f;    // lane 0 has no left halo
    const int y0b = y0 * 4, y1b = y1 * 4;          // byte offsets in a row

    // ---- t=0 init (only lane 0 holds mass) ----
    float a0=0.f, a1=0.f, a2=0.f, a3=0.f;
    if (lane == 0) { a0 = gp[BLANKc]+EPSc; a1 = gp[y0]+EPSc; }
    int e = 0;

    // ---- pre-zero rowbuf (wrapped/dormant slot reads become exact 0) ----
    {
        const float4 z = make_float4(0.f, 0.f, 0.f, 0.f);
        float4* rb4 = (float4*)rowbuf;             // 4160 float4 = 65*64
#pragma unroll
        for (int i = 0; i < 65; ++i) rb4[i*64 + lane] = z;
    }

    // ---- pre-stage rows 0..15 WITH EPS (coalesced float4 reads) ----
#pragma unroll
    for (int i = 0; i < 8; ++i) {
        const int f4  = i*64 + lane;               // 512 float4 across 16 rows
        const int row = f4 >> 5;                   // 32 float4 per row
        const int c4  = (f4 & 31) * 4;
        float4 v = *(const float4*)(gp + row*Cc + c4);
        float* dst = &rowbuf[row*RSTRIDE + c4];
        dst[0]=v.x+EPSc; dst[1]=v.y+EPSc; dst[2]=v.z+EPSc; dst[3]=v.w+EPSc;
    }
    // single wave: LDS writes/reads are program-ordered; no barrier needed.

    // ---- staging queue: rows 16..23 in flight ----
    float2 Q[QD];
#pragma unroll
    for (int k = 0; k < QD; ++k)
        Q[k] = *(const float2*)(gp + (16+k)*Cc + lane*2);

    // ---- incremental LDS byte offsets (pre-increment form) ----
    int swb = (((1 - lane) & (NSLOT-1)) * RSTRIDE - RSTRIDE) * 4;  // gather
    if (swb < 0) swb += SLOTB;
    int wswb = 15 * RSTRIDE * 4;                   // write: slot (n+15)&127
    const int lane8 = lane * 8;

    // ---- halo pipes: a3 every step (2-step slack); e per epoch ----
    float q2a = 0.f, q1a = 0.f;
    int ELa = 0, ELb = 0;

    auto body = [&](int n, int j, bool fzp) {
        // -- gather this step's probs (p+EPS staged), incremental address --
        swb += RSTRIDE*4; if (swb >= SLOTB) swb -= SLOTB;
        const float pb = *(const float*)(rb + swb + BLANKc*4);
        const float p0 = *(const float*)(rb + swb + y0b);
        const float p1 = *(const float*)(rb + swb + y1b);
        // -- stage row n+15 (loaded 8 steps ago, +EPS), reload row n+23 --
        wswb += RSTRIDE*4; if (wswb >= SLOTB) wswb -= SLOTB;
        float2 qv = Q[j & 7];
        qv.x += EPSc; qv.y += EPSc;
        *(float2*)(rb + wswb + lane8) = qv;
        int lr = n + 23; lr = lr > Tc-1 ? Tc-1 : lr;           // uniform/SALU
        Q[j & 7] = *(const float2*)(gp + lr*Cc + lane*2);
        // -- left-epoch select (compile-time by j): epoch floor((n-2)/4) --
        const int el = ((j == 0) || (j >= 5 && j <= 8) || (j >= 13)) ? ELb : ELa;
        // -- halo from left lane's step n-2 (2-step shuffle slack) --
        const float h1r = q2a; q2a = q1a;
        int d = el - e; d = d > 126 ? 126 : d;
        const float h1 = mh * ldexpf(h1r, d);
        const float n0 = (a0 + h1) * pb;
        const float n1 = (a1 + a0 + ms1*h1) * p0;
        const float n2 = (a2 + a1) * pb;
        const float n3 = (a3 + a2 + ms3*a1) * p1;
        bool upd = true;
        if (fzp) upd = (lane >= n - (Tc-1));       // freeze lanes past t=1023
        if (upd) { a0=n0; a1=n1; a2=n2; a3=n3; }
        if ((j & 3) == 3) {                        // renorm (pow2-exact)
            const float m = fmaxf(fmaxf(a0,a1), fmaxf(a2,a3));
            int ex = (int)((__float_as_uint(m) >> 23) & 0xFF) - 127;
            ex = (m > 0.0f) ? ex : (el - e);       // dormant: adopt left epoch
            a0 = ldexpf(a0,-ex); a1 = ldexpf(a1,-ex);
            a2 = ldexpf(a2,-ex); a3 = ldexpf(a3,-ex);
            e += ex;
        }
        // -- halo out: a3 every step (post-renorm on renorm steps) --
        q1a = __shfl_up(a3, 1, 64);
        if ((j & 3) == 3) {                        // e per epoch, 2-reg rotate
            const int es = __shfl_up(e, 1, 64);
            if (j == 3 || j == 11) ELb = es; else ELa = es;
        }
    };

    // ---- wave-steps n = 1..1073 (lane 50 ends t=1023 at n=1073) ----
    int n = 1;
    for (int c = 0; c < 63; ++c) {                 // n = 1..1008: no freeze
#pragma unroll
        for (int j = 0; j < 16; ++j) { body(n, j, false); ++n; }
    }
    for (int c = 0; c < 4; ++c) {                  // n = 1009..1072 (freeze
#pragma unroll                                     //  predicate inert <1024)
        for (int j = 0; j < 16; ++j) { body(n, j, true); ++n; }
    }
    body(n, 0, true);                              // n = 1073

    // ---- epilogue: loss = -ln( A[2L-1] + A[2L] ), A = a * 2^e ----
    if (lane < 51) {
        shA[4*lane+0] = a0; shA[4*lane+1] = a1;
        shA[4*lane+2] = a2; shA[4*lane+3] = a3;
        shE[lane] = e;
    }
    __syncthreads();                               // one-time, post-loop
    if (lane == 0) {
        const int L  = label_len[b];
        const int s1 = 2*L - 1, s2 = 2*L;
        const float v1 = shA[s1], v2 = shA[s2];
        const int   e1 = shE[s1 >> 2], e2 = shE[s2 >> 2];
        const int   em = e1 > e2 ? e1 : e2;
        const float sum = ldexpf(v1, e1-em) + ldexpf(v2, e2-em);
        const float r   = __log2f(sum) + (float)em;
        out[b] = -LN2f * r;
    }
}

extern "C" void kernel_launch(void* const* d_in, const int* in_sizes, int n_in,
                              void* d_out, int out_size, void* d_ws, size_t ws_size,
                              hipStream_t stream) {
    const float* y_pred    = (const float*)d_in[0];
    const int*   y_true    = (const int*)d_in[1];
    const int*   label_len = (const int*)d_in[2];
    float*       out       = (float*)d_out;
    ctc_skew_kernel<<<Bc, 64, 0, stream>>>(y_pred, y_true, label_len, out);
}